// Round 1
// baseline (181.068 us; speedup 1.0000x reference)
//
#include <hip/hip_runtime.h>

typedef __bf16 bf16;
typedef bf16 bf16x4 __attribute__((ext_vector_type(4)));
typedef bf16 bf16x8 __attribute__((ext_vector_type(8)));
typedef float f32x4 __attribute__((ext_vector_type(4)));

#define NB    128
#define NTOK  2048
#define INDIM 256
#define HIDW  128
#define NEXP  8
#define NMODE 4
#define KC    256
#define DC    64
#define NSYM  4096
#define CBS   88     // LDS row stride in bf16 elems (176 B: 16B-aligned, 2-way bank alias = free)
#define TOKT  128    // tokens per tile
#define TPBK  4      // tiles per block

// ---------------- Router: LN -> GELU MLP -> expert argmax + power scale (f64 for argmax fidelity) ----
__global__ __launch_bounds__(256)
void router_kernel(const float* __restrict__ phi,
                   const float* __restrict__ ln_g, const float* __restrict__ ln_b,
                   const float* __restrict__ W1, const float* __restrict__ b1,
                   const float* __restrict__ W2, const float* __restrict__ b2,
                   const float* __restrict__ We, const float* __restrict__ be,
                   const float* __restrict__ Wm, const float* __restrict__ bm,
                   float* __restrict__ scale_out, int* __restrict__ eidx_out)
{
  const int b = blockIdx.x, t = threadIdx.x;
  __shared__ double xs[INDIM];
  __shared__ double h1s[HIDW];
  __shared__ double h2s[HIDW];
  __shared__ double red4[4];
  __shared__ double lg[NEXP + NMODE];

  double v = (double)phi[b * INDIM + t];
  double s = v;
  #pragma unroll
  for (int off = 32; off; off >>= 1) s += __shfl_down(s, off);
  if ((t & 63) == 0) red4[t >> 6] = s;
  __syncthreads();
  double mu = (red4[0] + red4[1] + red4[2] + red4[3]) * (1.0 / 256.0);
  double dv = v - mu;
  double s2 = dv * dv;
  #pragma unroll
  for (int off = 32; off; off >>= 1) s2 += __shfl_down(s2, off);
  __syncthreads();
  if ((t & 63) == 0) red4[t >> 6] = s2;
  __syncthreads();
  double var = (red4[0] + red4[1] + red4[2] + red4[3]) * (1.0 / 256.0);
  xs[t] = dv * (1.0 / sqrt(var + 1e-5)) * (double)ln_g[t] + (double)ln_b[t];
  __syncthreads();

  if (t < HIDW) {
    double a = (double)b1[t];
    for (int i = 0; i < INDIM; ++i) a += xs[i] * (double)W1[i * HIDW + t];
    h1s[t] = a * 0.5 * (1.0 + erf(a * 0.70710678118654752440));
  }
  __syncthreads();
  if (t < HIDW) {
    double a = (double)b2[t];
    for (int i = 0; i < HIDW; ++i) a += h1s[i] * (double)W2[i * HIDW + t];
    h2s[t] = a * 0.5 * (1.0 + erf(a * 0.70710678118654752440));
  }
  __syncthreads();
  if (t < NEXP + NMODE) {
    double a;
    if (t < NEXP) {
      a = (double)be[t];
      for (int i = 0; i < HIDW; ++i) a += h2s[i] * (double)We[i * NEXP + t];
    } else {
      const int j = t - NEXP;
      a = (double)bm[j];
      for (int i = 0; i < HIDW; ++i) a += h2s[i] * (double)Wm[i * NMODE + j];
    }
    lg[t] = a;
  }
  __syncthreads();
  if (t == 0) {
    int best = 0; double bv = lg[0];
    for (int j = 1; j < NEXP; ++j) if (lg[j] > bv) { bv = lg[j]; best = j; }
    eidx_out[b] = best;
    double m = lg[NEXP];
    for (int j = 1; j < NMODE; ++j) m = fmax(m, lg[NEXP + j]);
    double den = 0.0, num = 0.0;
    for (int j = 0; j < NMODE; ++j) {
      double e = exp(lg[NEXP + j] - m);
      den += e; num += e * (0.25 * (j + 1));
    }
    scale_out[b] = (float)(num / den);
  }
}

// ---------------- Fused VQ: bf16 MFMA distances -> factorized softmax/soft-bits -> QAM demod ----
__global__ __launch_bounds__(256, 2)
void vq_kernel(const float* __restrict__ z, const float* __restrict__ codebooks,
               const float* __restrict__ scale_arr, const int* __restrict__ eidx,
               float* __restrict__ out)
{
  __shared__ __align__(16) bf16 cb_s[KC * CBS];      // 45056 B
  __shared__ float cn2_s[KC];                        //  1024 B  (2*||cb_k||^2)
  __shared__ __align__(16) bf16 z_s[TOKT * CBS];     // 22528 B
  __shared__ __align__(16) float sb_s[4][32 * 8];    //  4096 B  per-wave soft-bit bounce

  const int blk  = blockIdx.x;
  const int b    = blk >> 2;
  const int tg   = blk & 3;
  const int tid  = threadIdx.x;
  const int lane = tid & 63;
  const int wid  = tid >> 6;
  const int q    = lane >> 4;
  const int c    = lane & 15;

  // ---- stage codebook (thread = code row), bf16 + 2*norm ----
  {
    const int e = eidx[b];
    const float4* __restrict__ row = (const float4*)(codebooks + (size_t)e * KC * DC) + tid * 16;
    bf16* dst = cb_s + tid * CBS;
    float nrm = 0.f;
    #pragma unroll
    for (int i = 0; i < 16; ++i) {
      float4 v = row[i];
      bf16x4 p;
      p.x = (bf16)v.x; p.y = (bf16)v.y; p.z = (bf16)v.z; p.w = (bf16)v.w;
      *(bf16x4*)(dst + i * 4) = p;
      nrm += (float)p.x * (float)p.x + (float)p.y * (float)p.y
           + (float)p.z * (float)p.z + (float)p.w * (float)p.w;
    }
    cn2_s[tid] = 2.f * nrm;
  }
  const float scale_b = scale_arr[b];
  __syncthreads();

  const float cbit0 = (float)((c >> 3) & 1), cbit1 = (float)((c >> 2) & 1);
  const float cbit2 = (float)((c >> 1) & 1), cbit3 = (float)(c & 1);

  for (int tile = 0; tile < TPBK; ++tile) {
    const int n0 = tg * (TOKT * TPBK) + tile * TOKT;

    // ---- stage z tile (coalesced float4 -> bf16 LDS) ----
    {
      const float4* __restrict__ zsrc = (const float4*)(z + ((size_t)b * NTOK + n0) * DC);
      #pragma unroll
      for (int i = 0; i < 8; ++i) {
        int f = i * 256 + tid;
        float4 v = zsrc[f];
        bf16x4 p;
        p.x = (bf16)v.x; p.y = (bf16)v.y; p.z = (bf16)v.z; p.w = (bf16)v.w;
        *(bf16x4*)(z_s + (f >> 4) * CBS + (f & 15) * 4) = p;
      }
    }
    __syncthreads();

    // ---- MFMA: 32 tokens x 256 codes per wave ----
    const int tokbase = wid * 32;
    bf16x8 afr[2][2];
    #pragma unroll
    for (int mt = 0; mt < 2; ++mt)
      #pragma unroll
      for (int ks = 0; ks < 2; ++ks)
        afr[mt][ks] = *(const bf16x8*)(z_s + (tokbase + mt * 16 + c) * CBS + ks * 32 + q * 8);

    f32x4 acc[2][16];
    #pragma unroll
    for (int mt = 0; mt < 2; ++mt)
      #pragma unroll
      for (int t = 0; t < 16; ++t)
        acc[mt][t] = (f32x4){0.f, 0.f, 0.f, 0.f};

    #pragma unroll
    for (int t = 0; t < 16; ++t) {
      #pragma unroll
      for (int ks = 0; ks < 2; ++ks) {
        bf16x8 bfr = *(const bf16x8*)(cb_s + (t * 16 + c) * CBS + ks * 32 + q * 8);
        acc[0][t] = __builtin_amdgcn_mfma_f32_16x16x32_bf16(afr[0][ks], bfr, acc[0][t], 0, 0, 0);
        acc[1][t] = __builtin_amdgcn_mfma_f32_16x16x32_bf16(afr[1][ks], bfr, acc[1][t], 0, 0, 0);
      }
    }

    float cn2[16];
    #pragma unroll
    for (int t = 0; t < 16; ++t) cn2[t] = cn2_s[t * 16 + c];

    // ---- factorized VQ softmax + soft bits (per D-row r of each M-tile) ----
    #pragma unroll
    for (int mt = 0; mt < 2; ++mt) {
      #pragma unroll
      for (int r = 0; r < 4; ++r) {
        float M = -1e30f;
        #pragma unroll
        for (int t = 0; t < 16; ++t) M = fmaxf(M, 4.f * acc[mt][t][r] - cn2[t]);
        M = fmaxf(M, __shfl_xor(M, 1));
        M = fmaxf(M, __shfl_xor(M, 2));
        M = fmaxf(M, __shfl_xor(M, 4));
        M = fmaxf(M, __shfl_xor(M, 8));
        float F = 0.f, s0 = 0.f, s1 = 0.f, s2 = 0.f, s3 = 0.f;
        #pragma unroll
        for (int t = 0; t < 16; ++t) {
          float ev = __expf(4.f * acc[mt][t][r] - cn2[t] - M);
          F += ev;
          if (t & 8) s0 += ev;
          if (t & 4) s1 += ev;
          if (t & 2) s2 += ev;
          if (t & 1) s3 += ev;
        }
        float w4 = cbit0 * F, w5 = cbit1 * F, w6 = cbit2 * F, w7 = cbit3 * F;
        float dn = F;
        #define BFLY(x) x += __shfl_xor(x, 1); x += __shfl_xor(x, 2); x += __shfl_xor(x, 4); x += __shfl_xor(x, 8);
        BFLY(dn) BFLY(s0) BFLY(s1) BFLY(s2) BFLY(s3) BFLY(w4) BFLY(w5) BFLY(w6) BFLY(w7)
        #undef BFLY
        if (c < 8) {
          float num = (c == 0) ? s0 : (c == 1) ? s1 : (c == 2) ? s2 : (c == 3) ? s3
                    : (c == 4) ? w4 : (c == 5) ? w5 : (c == 6) ? w6 : w7;
          sb_s[wid][(mt * 16 + q * 4 + r) * 8 + c] = num * __builtin_amdgcn_rcpf(dn);
        }
      }
    }

    // ---- 16-QAM soft demod: lane = (token, symbol) ----
    {
      const int tok = lane >> 1, sym = lane & 1;
      const float* sb = &sb_s[wid][tok * 8 + sym * 4];
      float u0 = sb[0], u1 = sb[1], u2 = sb[2], u3 = sb[3];
      float wsum = 0.f, xa = 0.f, ya = 0.f;
      #pragma unroll
      for (int m = 0; m < 16; ++m) {
        float su = 0.f;
        if (m & 8) su += u0;
        if (m & 4) su += u1;
        if (m & 2) su += u2;
        if (m & 1) su += u3;
        const float pc = (float)__builtin_popcount(m);
        float ev = __expf(4.f * su - 2.f * pc);
        wsum += ev;
        xa += ev * (float)(2 * (m >> 2) - 3);
        ya += ev * (float)(2 * (m & 3) - 3);
      }
      const float fac = scale_b * 0.23570226039551584f * __builtin_amdgcn_rcpf(wsum);
      const int n = n0 + wid * 32 + tok;
      float2* op = (float2*)(out + (((size_t)b * NSYM) + 2 * (size_t)n + sym) * 2);
      *op = make_float2(xa * fac, ya * fac);
    }
    __syncthreads();   // before next tile overwrites z_s
  }
}

extern "C" void kernel_launch(void* const* d_in, const int* in_sizes, int n_in,
                              void* d_out, int out_size, void* d_ws, size_t ws_size,
                              hipStream_t stream) {
  const float* phi  = (const float*)d_in[0];
  const float* z    = (const float*)d_in[1];
  const float* ln_g = (const float*)d_in[2];
  const float* ln_b = (const float*)d_in[3];
  const float* W1   = (const float*)d_in[4];
  const float* b1   = (const float*)d_in[5];
  const float* W2   = (const float*)d_in[6];
  const float* b2   = (const float*)d_in[7];
  const float* We   = (const float*)d_in[8];
  const float* be   = (const float*)d_in[9];
  const float* Wm   = (const float*)d_in[10];
  const float* bm   = (const float*)d_in[11];
  const float* cbk  = (const float*)d_in[12];
  float* out   = (float*)d_out;
  float* scale = (float*)d_ws;
  int*   eidx  = (int*)((char*)d_ws + 512);

  router_kernel<<<NB, 256, 0, stream>>>(phi, ln_g, ln_b, W1, b1, W2, b2,
                                        We, be, Wm, bm, scale, eidx);
  vq_kernel<<<NB * 4, 256, 0, stream>>>(z, cbk, scale, eidx, out);
}